// Round 4
// baseline (572.244 us; speedup 1.0000x reference)
//
#include <hip/hip_runtime.h>

#define NN 100000
#define EE 600000
#define GG 1000
#define NB ((NN + 255) / 256)   // 391 blocks for node-sized scans

// ---------------- setup kernels (CSR build + norm) ----------------

__global__ void k_init(int* cnt, int* fillc, int* gstart) {
  int i = blockIdx.x * 256 + threadIdx.x;
  if (i < NN) { cnt[i] = 0; fillc[i] = 0; }
  if (i <= GG) gstart[i] = NN;   // default: empty graphs past the last batch id
}

__global__ void k_count(const int* __restrict__ dst, int* cnt) {
  int e = blockIdx.x * 256 + threadIdx.x;
  if (e < EE) atomicAdd(&cnt[dst[e]], 1);
}

__global__ void k_dinv(const int* __restrict__ cnt, float* dinv) {
  int i = blockIdx.x * 256 + threadIdx.x;
  if (i < NN) dinv[i] = rsqrtf((float)(cnt[i] + 1));  // +1 = self loop; deg>=1 always
}

__global__ void k_scan1(const int* __restrict__ cnt, int* rowptr, int* bsum) {
  __shared__ int s[256];
  int tid = threadIdx.x;
  int i = blockIdx.x * 256 + tid;
  int v = (i < NN) ? cnt[i] : 0;
  s[tid] = v;
  __syncthreads();
  for (int off = 1; off < 256; off <<= 1) {
    int t = (tid >= off) ? s[tid - off] : 0;
    __syncthreads();
    s[tid] += t;
    __syncthreads();
  }
  if (i < NN) rowptr[i] = s[tid] - v;          // block-local exclusive
  if (tid == 255) bsum[blockIdx.x] = s[255];   // block total
}

__global__ void k_scan2(int* bsum) {
  __shared__ int s[512];
  int tid = threadIdx.x;
  int v = (tid < NB) ? bsum[tid] : 0;
  s[tid] = v;
  __syncthreads();
  for (int off = 1; off < 512; off <<= 1) {
    int t = (tid >= off) ? s[tid - off] : 0;
    __syncthreads();
    s[tid] += t;
    __syncthreads();
  }
  if (tid < NB) bsum[tid] = s[tid] - v;        // exclusive over block sums
}

__global__ void k_scan3(int* rowptr, const int* __restrict__ bsum) {
  int i = blockIdx.x * 256 + threadIdx.x;
  if (i < NN) rowptr[i] += bsum[blockIdx.x];
  if (i == 0) rowptr[NN] = EE;                 // total edge count is fixed
}

__global__ void k_fill(const int* __restrict__ src, const int* __restrict__ dst,
                       const int* __restrict__ rowptr, int* fillc,
                       const float* __restrict__ dinv,
                       int* csr_src, float* csr_w) {
  int e = blockIdx.x * 256 + threadIdx.x;
  if (e >= EE) return;
  int s = src[e], d = dst[e];
  int pos = rowptr[d] + atomicAdd(&fillc[d], 1);
  csr_src[pos] = s;
  csr_w[pos] = dinv[s] * dinv[d];
}

// batch is sorted: gstart[g] = first node index with batch >= g (boundary scan)
__global__ void k_gbound(const int* __restrict__ batch, int* gstart) {
  int i = blockIdx.x * 256 + threadIdx.x;
  if (i >= NN) return;
  int b = batch[i];
  if (i == 0) {
    for (int g = 0; g <= b; ++g) gstart[g] = 0;
  } else {
    int prev = batch[i - 1];
    for (int g = prev + 1; g <= b; ++g) gstart[g] = i;  // covers empty graphs too
  }
}

// ---------------- layer kernels ----------------

// layer-0 linear: [N,4] @ [4,128] -> hout (no bias; bias added in aggregate)
__global__ void k_mm0(const float* __restrict__ x, const float* __restrict__ W0,
                      float* __restrict__ hout) {
  int idx = blockIdx.x * 256 + threadIdx.x;
  if (idx >= NN * 128) return;
  int node = idx >> 7, j = idx & 127;
  const float* xr = x + node * 4;
  float s = xr[0] * W0[j];
  s = fmaf(xr[1], W0[128 + j], s);
  s = fmaf(xr[2], W0[256 + j], s);
  s = fmaf(xr[3], W0[384 + j], s);
  hout[idx] = s;
}

// [N,128] @ [128,128], relu fused on input. 128x128 block tile, 8x8/thread,
// K chunked by 32. A stored TRANSPOSED in LDS (AsT[k][row], stride 132 keeps
// float4 alignment + staging-store conflicts at 4-way) so the per-k fragment
// read is 2x ds_read_b128 (4 distinct addrs/wave = broadcast). W chunk staged
// in LDS (k-major); col split tx*4 / 64+tx*4 makes B reads 2-way = free.
#define ASTRIDE 132
__global__ __launch_bounds__(256, 4) void k_mm128(const float* __restrict__ hin,
                                                  const float* __restrict__ W,
                                                  float* __restrict__ hout) {
  __shared__ float AsT[32 * ASTRIDE];  // 16.9 KB
  __shared__ float Ws[32 * 128];       // 16 KB
  int tid = threadIdx.x;
  int row0 = blockIdx.x * 128;
  int tx = tid & 15, ty = tid >> 4;
  float acc[8][8];
  #pragma unroll
  for (int i = 0; i < 8; ++i)
    #pragma unroll
    for (int j = 0; j < 8; ++j) acc[i][j] = 0.f;

  for (int kc = 0; kc < 4; ++kc) {
    #pragma unroll
    for (int tt = 0; tt < 4; ++tt) {
      int idx = tt * 1024 + tid * 4;
      // A chunk: 128 rows x 32 k, transpose on store
      int r = idx >> 5, kk = idx & 31;
      int gr = row0 + r;
      float4 v = make_float4(0.f, 0.f, 0.f, 0.f);
      if (gr < NN) v = *(const float4*)(hin + (size_t)gr * 128 + kc * 32 + kk);
      v.x = fmaxf(v.x, 0.f); v.y = fmaxf(v.y, 0.f);
      v.z = fmaxf(v.z, 0.f); v.w = fmaxf(v.w, 0.f);
      AsT[(kk + 0) * ASTRIDE + r] = v.x;
      AsT[(kk + 1) * ASTRIDE + r] = v.y;
      AsT[(kk + 2) * ASTRIDE + r] = v.z;
      AsT[(kk + 3) * ASTRIDE + r] = v.w;
      // W chunk: 32 k x 128 cols, already k-major
      int wk = idx >> 7, wc = idx & 127;
      *(float4*)&Ws[wk * 128 + wc] =
          *(const float4*)(W + (size_t)(kc * 32 + wk) * 128 + wc);
    }
    __syncthreads();
    #pragma unroll 4
    for (int kk = 0; kk < 32; ++kk) {
      float4 a0 = *(const float4*)&AsT[kk * ASTRIDE + ty * 8];
      float4 a1 = *(const float4*)&AsT[kk * ASTRIDE + ty * 8 + 4];
      float4 b0 = *(const float4*)&Ws[kk * 128 + tx * 4];
      float4 b1 = *(const float4*)&Ws[kk * 128 + 64 + tx * 4];
      float a[8] = {a0.x, a0.y, a0.z, a0.w, a1.x, a1.y, a1.z, a1.w};
      float b[8] = {b0.x, b0.y, b0.z, b0.w, b1.x, b1.y, b1.z, b1.w};
      #pragma unroll
      for (int i = 0; i < 8; ++i)
        #pragma unroll
        for (int j = 0; j < 8; ++j)
          acc[i][j] = fmaf(a[i], b[j], acc[i][j]);
    }
    __syncthreads();
  }
  #pragma unroll
  for (int i = 0; i < 8; ++i) {
    int gr = row0 + ty * 8 + i;
    if (gr < NN) {
      *(float4*)(hout + (size_t)gr * 128 + tx * 4) =
          make_float4(acc[i][0], acc[i][1], acc[i][2], acc[i][3]);
      *(float4*)(hout + (size_t)gr * 128 + 64 + tx * 4) =
          make_float4(acc[i][4], acc[i][5], acc[i][6], acc[i][7]);
    }
  }
}

// out[i] = b + dinv[i]^2 * hlin[i] + sum_e w[e] * hlin[csr_src[e]]
// one wave per node, float2 per lane (64*2 = 128 cols).
__global__ __launch_bounds__(256) void k_aggregate(const float* __restrict__ hlin,
                                                   const int* __restrict__ rowptr,
                                                   const int* __restrict__ csr_src,
                                                   const float* __restrict__ csr_w,
                                                   const float* __restrict__ dinv,
                                                   const float* __restrict__ bias,
                                                   float* __restrict__ hout) {
  int node = blockIdx.x * 4 + (threadIdx.x >> 6);
  int lane = threadIdx.x & 63;
  if (node >= NN) return;
  float di = dinv[node];
  float sw = di * di;
  float2 hv = *(const float2*)(hlin + (size_t)node * 128 + lane * 2);
  float2 bv = *(const float2*)(bias + lane * 2);
  float2 acc = make_float2(fmaf(sw, hv.x, bv.x), fmaf(sw, hv.y, bv.y));
  int beg = rowptr[node], end = rowptr[node + 1];
  for (int base = beg; base < end; base += 64) {
    int m = end - base; if (m > 64) m = 64;           // wave-uniform
    int li = base + (lane < m ? lane : m - 1);        // clamp keeps loads in-bounds
    int idxv = csr_src[li];                           // one coalesced load / chunk
    int wbits = __float_as_int(csr_w[li]);
    int j = 0;
    for (; j + 4 <= m; j += 4) {                      // 4 gathers in flight
      int s0 = __builtin_amdgcn_readlane(idxv, j + 0);
      int s1 = __builtin_amdgcn_readlane(idxv, j + 1);
      int s2 = __builtin_amdgcn_readlane(idxv, j + 2);
      int s3 = __builtin_amdgcn_readlane(idxv, j + 3);
      float w0 = __int_as_float(__builtin_amdgcn_readlane(wbits, j + 0));
      float w1 = __int_as_float(__builtin_amdgcn_readlane(wbits, j + 1));
      float w2 = __int_as_float(__builtin_amdgcn_readlane(wbits, j + 2));
      float w3 = __int_as_float(__builtin_amdgcn_readlane(wbits, j + 3));
      float2 v0 = *(const float2*)(hlin + (size_t)s0 * 128 + lane * 2);
      float2 v1 = *(const float2*)(hlin + (size_t)s1 * 128 + lane * 2);
      float2 v2 = *(const float2*)(hlin + (size_t)s2 * 128 + lane * 2);
      float2 v3 = *(const float2*)(hlin + (size_t)s3 * 128 + lane * 2);
      acc.x = fmaf(w0, v0.x, acc.x); acc.y = fmaf(w0, v0.y, acc.y);
      acc.x = fmaf(w1, v1.x, acc.x); acc.y = fmaf(w1, v1.y, acc.y);
      acc.x = fmaf(w2, v2.x, acc.x); acc.y = fmaf(w2, v2.y, acc.y);
      acc.x = fmaf(w3, v3.x, acc.x); acc.y = fmaf(w3, v3.y, acc.y);
    }
    if (j + 2 <= m) {                                 // uniform-branch pair tail
      int s0 = __builtin_amdgcn_readlane(idxv, j + 0);
      int s1 = __builtin_amdgcn_readlane(idxv, j + 1);
      float w0 = __int_as_float(__builtin_amdgcn_readlane(wbits, j + 0));
      float w1 = __int_as_float(__builtin_amdgcn_readlane(wbits, j + 1));
      float2 v0 = *(const float2*)(hlin + (size_t)s0 * 128 + lane * 2);
      float2 v1 = *(const float2*)(hlin + (size_t)s1 * 128 + lane * 2);
      acc.x = fmaf(w0, v0.x, acc.x); acc.y = fmaf(w0, v0.y, acc.y);
      acc.x = fmaf(w1, v1.x, acc.x); acc.y = fmaf(w1, v1.y, acc.y);
      j += 2;
    }
    if (j < m) {                                      // uniform-branch single tail
      int s0 = __builtin_amdgcn_readlane(idxv, j);
      float w0 = __int_as_float(__builtin_amdgcn_readlane(wbits, j));
      float2 v0 = *(const float2*)(hlin + (size_t)s0 * 128 + lane * 2);
      acc.x = fmaf(w0, v0.x, acc.x); acc.y = fmaf(w0, v0.y, acc.y);
    }
  }
  *(float2*)(hout + (size_t)node * 128 + lane * 2) = acc;
}

// ---------------- fused pool (segmented, no atomics) + MLP head ----------------
__global__ __launch_bounds__(256) void k_poolmlp(const float* __restrict__ h4,
                                                 const int* __restrict__ gstart,
                                                 const float* __restrict__ xs,
                                                 const float* __restrict__ Wl1,
                                                 const float* __restrict__ bl1,
                                                 const float* __restrict__ Wl2,
                                                 const float* __restrict__ bl2,
                                                 float* __restrict__ out) {
  __shared__ float4 part[8][32];
  __shared__ float pooled[128];
  int g = blockIdx.x;
  int beg = gstart[g], end = gstart[g + 1];
  int tid = threadIdx.x;
  int cg = tid & 31;        // float4 column group (32 * 4 = 128 cols)
  int rg = tid >> 5;        // 8 rows per iteration
  float4 acc = make_float4(0.f, 0.f, 0.f, 0.f);
  for (int i = beg + rg; i < end; i += 8) {
    float4 v = *(const float4*)(h4 + (size_t)i * 128 + cg * 4);  // 4KB/iter coalesced
    acc.x += fmaxf(v.x, 0.f); acc.y += fmaxf(v.y, 0.f);
    acc.z += fmaxf(v.z, 0.f); acc.w += fmaxf(v.w, 0.f);
  }
  part[rg][cg] = acc;
  __syncthreads();
  if (tid < 32) {
    float4 s = part[0][tid];
    #pragma unroll
    for (int r = 1; r < 8; ++r) {
      float4 v = part[r][tid];
      s.x += v.x; s.y += v.y; s.z += v.z; s.w += v.w;
    }
    float sc = 1.f / fmaxf((float)(end - beg), 1.f);
    pooled[tid * 4 + 0] = s.x * sc;
    pooled[tid * 4 + 1] = s.y * sc;
    pooled[tid * 4 + 2] = s.z * sc;
    pooled[tid * 4 + 3] = s.w * sc;
  }
  __syncthreads();
  if (tid < 64) {   // exactly wave 0
    float hj = bl1[tid];
    #pragma unroll 4
    for (int k = 0; k < 128; ++k) hj = fmaf(pooled[k], Wl1[k * 64 + tid], hj);
    const float* xr = xs + g * 4;
    #pragma unroll
    for (int k = 0; k < 4; ++k) hj = fmaf(xr[k], Wl1[(128 + k) * 64 + tid], hj);
    hj = fmaxf(hj, 0.f);
    float val = hj * Wl2[tid];
    #pragma unroll
    for (int off = 32; off > 0; off >>= 1) val += __shfl_down(val, off);
    if (tid == 0) out[g] = val + bl2[0];
  }
}

// ---------------- launcher ----------------

extern "C" void kernel_launch(void* const* d_in, const int* in_sizes, int n_in,
                              void* d_out, int out_size, void* d_ws, size_t ws_size,
                              hipStream_t stream) {
  const float* x    = (const float*)d_in[0];
  const int*   ei   = (const int*)d_in[1];
  const float* xs   = (const float*)d_in[2];
  const int*   batch= (const int*)d_in[3];
  const float* W0   = (const float*)d_in[4];
  const float* b0   = (const float*)d_in[5];
  const float* W1   = (const float*)d_in[6];
  const float* b1   = (const float*)d_in[7];
  const float* W2   = (const float*)d_in[8];
  const float* b2   = (const float*)d_in[9];
  const float* W3   = (const float*)d_in[10];
  const float* b3   = (const float*)d_in[11];
  const float* Wl1  = (const float*)d_in[12];
  const float* bl1  = (const float*)d_in[13];
  const float* Wl2  = (const float*)d_in[14];
  const float* bl2  = (const float*)d_in[15];
  const int* srcA = ei;        // edge_index[0]
  const int* dstA = ei + EE;   // edge_index[1]
  float* out = (float*)d_out;

  char* p = (char*)d_ws;
  auto take = [&](size_t bytes) { char* q = p; p += (bytes + 255) & ~(size_t)255; return q; };
  float* hA    = (float*)take((size_t)NN * 128 * 4);
  float* hB    = (float*)take((size_t)NN * 128 * 4);
  int*   cnt   = (int*)take((size_t)NN * 4);
  float* dinv  = (float*)take((size_t)NN * 4);
  int*   rowptr= (int*)take((size_t)(NN + 1) * 4);
  int*   fillc = (int*)take((size_t)NN * 4);
  int*   csr_s = (int*)take((size_t)EE * 4);
  float* csr_w = (float*)take((size_t)EE * 4);
  int*   bsum  = (int*)take(512 * 4);
  int*   gstart= (int*)take((size_t)(GG + 1) * 4);

  // setup: degree, norm, CSR-by-dst, graph boundaries
  k_init<<<NB, 256, 0, stream>>>(cnt, fillc, gstart);
  k_count<<<(EE + 255) / 256, 256, 0, stream>>>(dstA, cnt);
  k_dinv<<<NB, 256, 0, stream>>>(cnt, dinv);
  k_scan1<<<NB, 256, 0, stream>>>(cnt, rowptr, bsum);
  k_scan2<<<1, 512, 0, stream>>>(bsum);
  k_scan3<<<NB, 256, 0, stream>>>(rowptr, bsum);
  k_fill<<<(EE + 255) / 256, 256, 0, stream>>>(srcA, dstA, rowptr, fillc, dinv, csr_s, csr_w);
  k_gbound<<<NB, 256, 0, stream>>>(batch, gstart);

  // layer 0: x @ W0 -> hA; aggregate(hA) + b0 -> hB (pre-relu)
  k_mm0<<<(NN * 128 + 255) / 256, 256, 0, stream>>>(x, W0, hA);
  k_aggregate<<<(NN + 3) / 4, 256, 0, stream>>>(hA, rowptr, csr_s, csr_w, dinv, b0, hB);
  // layers 1-3: relu fused into matmul A-load
  k_mm128<<<(NN + 127) / 128, 256, 0, stream>>>(hB, W1, hA);
  k_aggregate<<<(NN + 3) / 4, 256, 0, stream>>>(hA, rowptr, csr_s, csr_w, dinv, b1, hB);
  k_mm128<<<(NN + 127) / 128, 256, 0, stream>>>(hB, W2, hA);
  k_aggregate<<<(NN + 3) / 4, 256, 0, stream>>>(hA, rowptr, csr_s, csr_w, dinv, b2, hB);
  k_mm128<<<(NN + 127) / 128, 256, 0, stream>>>(hB, W3, hA);
  k_aggregate<<<(NN + 3) / 4, 256, 0, stream>>>(hA, rowptr, csr_s, csr_w, dinv, b3, hB);

  // fused pool + head MLP (no atomics)
  k_poolmlp<<<GG, 256, 0, stream>>>(hB, gstart, xs, Wl1, bl1, Wl2, bl2, out);
}

// Round 5
// 414.096 us; speedup vs baseline: 1.3819x; 1.3819x over previous
//
#include <hip/hip_runtime.h>

#define NN 100000
#define EE 600000
#define GG 1000
#define NB ((NN + 255) / 256)   // 391 blocks for node-sized scans

typedef __bf16 bf16x8 __attribute__((ext_vector_type(8)));
typedef float f32x4 __attribute__((ext_vector_type(4)));
typedef unsigned int u32;

__device__ inline float2 bf2_to_f2(u32 u) {
  return make_float2(__uint_as_float(u << 16), __uint_as_float(u & 0xffff0000u));
}
__device__ inline u32 f2_to_bf2(float a, float b) {
  union { __bf16 h[2]; u32 u; } pk;
  pk.h[0] = (__bf16)a; pk.h[1] = (__bf16)b;   // RNE converts
  return pk.u;
}

// ---------------- setup kernels (CSR build + norm) ----------------

__global__ void k_init(int* cnt, int* fillc, int* gstart) {
  int i = blockIdx.x * 256 + threadIdx.x;
  if (i < NN) { cnt[i] = 0; fillc[i] = 0; }
  if (i <= GG) gstart[i] = NN;   // default: empty graphs past the last batch id
}

__global__ void k_count(const int* __restrict__ dst, int* cnt) {
  int e = blockIdx.x * 256 + threadIdx.x;
  if (e < EE) atomicAdd(&cnt[dst[e]], 1);
}

__global__ void k_dinv(const int* __restrict__ cnt, float* dinv) {
  int i = blockIdx.x * 256 + threadIdx.x;
  if (i < NN) dinv[i] = rsqrtf((float)(cnt[i] + 1));  // +1 = self loop
}

__global__ void k_scan1(const int* __restrict__ cnt, int* rowptr, int* bsum) {
  __shared__ int s[256];
  int tid = threadIdx.x;
  int i = blockIdx.x * 256 + tid;
  int v = (i < NN) ? cnt[i] : 0;
  s[tid] = v;
  __syncthreads();
  for (int off = 1; off < 256; off <<= 1) {
    int t = (tid >= off) ? s[tid - off] : 0;
    __syncthreads();
    s[tid] += t;
    __syncthreads();
  }
  if (i < NN) rowptr[i] = s[tid] - v;
  if (tid == 255) bsum[blockIdx.x] = s[255];
}

__global__ void k_scan2(int* bsum) {
  __shared__ int s[512];
  int tid = threadIdx.x;
  int v = (tid < NB) ? bsum[tid] : 0;
  s[tid] = v;
  __syncthreads();
  for (int off = 1; off < 512; off <<= 1) {
    int t = (tid >= off) ? s[tid - off] : 0;
    __syncthreads();
    s[tid] += t;
    __syncthreads();
  }
  if (tid < NB) bsum[tid] = s[tid] - v;
}

__global__ void k_scan3(int* rowptr, const int* __restrict__ bsum) {
  int i = blockIdx.x * 256 + threadIdx.x;
  if (i < NN) rowptr[i] += bsum[blockIdx.x];
  if (i == 0) rowptr[NN] = EE;
}

__global__ void k_fill(const int* __restrict__ src, const int* __restrict__ dst,
                       const int* __restrict__ rowptr, int* fillc,
                       const float* __restrict__ dinv,
                       int* csr_src, float* csr_w) {
  int e = blockIdx.x * 256 + threadIdx.x;
  if (e >= EE) return;
  int s = src[e], d = dst[e];
  int pos = rowptr[d] + atomicAdd(&fillc[d], 1);
  csr_src[pos] = s;
  csr_w[pos] = dinv[s] * dinv[d];
}

__global__ void k_gbound(const int* __restrict__ batch, int* gstart) {
  int i = blockIdx.x * 256 + threadIdx.x;
  if (i >= NN) return;
  int b = batch[i];
  if (i == 0) {
    for (int g = 0; g <= b; ++g) gstart[g] = 0;
  } else {
    int prev = batch[i - 1];
    for (int g = prev + 1; g <= b; ++g) gstart[g] = i;
  }
}

// transpose W [128k x 128n] fp32 -> Wt [n][k] bf16 (one-time per layer)
__global__ void k_wprep(const float* __restrict__ W, __bf16* __restrict__ Wt) {
  int idx = blockIdx.x * 256 + threadIdx.x;   // 16384
  int n = idx >> 7, k = idx & 127;
  Wt[(size_t)n * 128 + k] = (__bf16)W[(size_t)k * 128 + n];
}

// ---------------- layer kernels ----------------

// layer-0 linear: [N,4] @ [4,128] -> bf16 hout (bias added in aggregate)
__global__ void k_mm0(const float* __restrict__ x, const float* __restrict__ W0,
                      __bf16* __restrict__ hout) {
  int idx = blockIdx.x * 256 + threadIdx.x;
  if (idx >= NN * 128) return;
  int node = idx >> 7, j = idx & 127;
  const float* xr = x + node * 4;
  float s = xr[0] * W0[j];
  s = fmaf(xr[1], W0[128 + j], s);
  s = fmaf(xr[2], W0[256 + j], s);
  s = fmaf(xr[3], W0[384 + j], s);
  hout[idx] = (__bf16)s;
}

// MFMA GEMM: hout[N,128] = hin[N,128] @ W, bf16 in / bf16 out, fp32 accum.
// Tile 128 rows/block, 4 waves; wave w owns rows [w*32, w*32+32).
// A-frag layout (16x16x32): A[m=lane&15][k=(lane>>4)*8+j] -> row-major LDS,
// 16B contiguous reads. B-frag: B[k=(lane>>4)*8+j][n=lane&15] -> Wt[n][k]
// global loads (L1-hot, 32KB), ALL 32 b-frags held in registers so the
// K-loop does only 8 ds_read_b128 per wave vs 64 MFMAs -> MFMA-bound.
#define LDSPAD 136   // bf16 elems/row; row stride 272B (16B-aligned), even bank spread
__global__ __launch_bounds__(256) void k_mfma(const __bf16* __restrict__ hin,
                                              const __bf16* __restrict__ Wt,
                                              __bf16* __restrict__ hout) {
  __shared__ __bf16 As[128 * LDSPAD];   // 34 KB
  int tid = threadIdx.x;
  int row0 = blockIdx.x * 128;
  int lane = tid & 63, w = tid >> 6;
  int ln = lane & 15, quad = lane >> 4;

  // all B fragments in registers (8 ntiles x 4 kchunks x 4 VGPR = 128 VGPR)
  bf16x8 bfrag[8][4];
  #pragma unroll
  for (int nt = 0; nt < 8; ++nt)
    #pragma unroll
    for (int kc = 0; kc < 4; ++kc)
      bfrag[nt][kc] = *(const bf16x8*)(Wt + (size_t)(nt * 16 + ln) * 128 + kc * 32 + quad * 8);

  // stage A tile: straight bf16 copy, 16B per thread per iter, coalesced
  #pragma unroll
  for (int i = 0; i < 8; ++i) {
    int eb = (i * 256 + tid) * 8;       // element base 0..16383
    int r = eb >> 7, c = eb & 127;
    int gr = row0 + r;
    uint4 v = make_uint4(0, 0, 0, 0);
    if (gr < NN) v = *(const uint4*)(hin + (size_t)gr * 128 + c);
    *(uint4*)&As[r * LDSPAD + c] = v;
  }
  __syncthreads();

  f32x4 acc[2][8];
  #pragma unroll
  for (int rt = 0; rt < 2; ++rt)
    #pragma unroll
    for (int nt = 0; nt < 8; ++nt) acc[rt][nt] = (f32x4){0.f, 0.f, 0.f, 0.f};

  #pragma unroll
  for (int kc = 0; kc < 4; ++kc) {
    bf16x8 a0 = *(const bf16x8*)&As[(w * 32 + ln) * LDSPAD + kc * 32 + quad * 8];
    bf16x8 a1 = *(const bf16x8*)&As[(w * 32 + 16 + ln) * LDSPAD + kc * 32 + quad * 8];
    #pragma unroll
    for (int nt = 0; nt < 8; ++nt) {
      acc[0][nt] = __builtin_amdgcn_mfma_f32_16x16x32_bf16(a0, bfrag[nt][kc], acc[0][nt], 0, 0, 0);
      acc[1][nt] = __builtin_amdgcn_mfma_f32_16x16x32_bf16(a1, bfrag[nt][kc], acc[1][nt], 0, 0, 0);
    }
  }

  // C layout: row=(lane>>4)*4+reg, col=lane&15 (m89-verified)
  #pragma unroll
  for (int rt = 0; rt < 2; ++rt)
    #pragma unroll
    for (int nt = 0; nt < 8; ++nt)
      #pragma unroll
      for (int reg = 0; reg < 4; ++reg) {
        int gr = row0 + w * 32 + rt * 16 + quad * 4 + reg;
        if (gr < NN)
          hout[(size_t)gr * 128 + nt * 16 + ln] = (__bf16)acc[rt][nt][reg];
      }
}

// out[i] = relu(b + dinv[i]^2*hlin[i] + sum_e w[e]*hlin[src[e]]) -> bf16
// hlin/hout are bf16 viewed as u32 pairs: 4B/lane, 256B/row coalesced.
__global__ __launch_bounds__(256) void k_aggregate(const u32* __restrict__ hlin2,
                                                   const int* __restrict__ rowptr,
                                                   const int* __restrict__ csr_src,
                                                   const float* __restrict__ csr_w,
                                                   const float* __restrict__ dinv,
                                                   const float* __restrict__ bias,
                                                   u32* __restrict__ hout2) {
  int node = blockIdx.x * 4 + (threadIdx.x >> 6);
  int lane = threadIdx.x & 63;
  if (node >= NN) return;
  float di = dinv[node];
  float sw = di * di;
  float2 hv = bf2_to_f2(hlin2[(size_t)node * 64 + lane]);
  float2 bv = *(const float2*)(bias + lane * 2);
  float2 acc = make_float2(fmaf(sw, hv.x, bv.x), fmaf(sw, hv.y, bv.y));
  int beg = rowptr[node], end = rowptr[node + 1];
  for (int base = beg; base < end; base += 64) {
    int m = end - base; if (m > 64) m = 64;           // wave-uniform
    int li = base + (lane < m ? lane : m - 1);        // clamp keeps loads in-bounds
    int idxv = csr_src[li];                           // one coalesced load / chunk
    int wbits = __float_as_int(csr_w[li]);
    int j = 0;
    for (; j + 4 <= m; j += 4) {                      // 4 gathers in flight
      int s0 = __builtin_amdgcn_readlane(idxv, j + 0);
      int s1 = __builtin_amdgcn_readlane(idxv, j + 1);
      int s2 = __builtin_amdgcn_readlane(idxv, j + 2);
      int s3 = __builtin_amdgcn_readlane(idxv, j + 3);
      float w0 = __int_as_float(__builtin_amdgcn_readlane(wbits, j + 0));
      float w1 = __int_as_float(__builtin_amdgcn_readlane(wbits, j + 1));
      float w2 = __int_as_float(__builtin_amdgcn_readlane(wbits, j + 2));
      float w3 = __int_as_float(__builtin_amdgcn_readlane(wbits, j + 3));
      u32 u0 = hlin2[(size_t)s0 * 64 + lane];
      u32 u1 = hlin2[(size_t)s1 * 64 + lane];
      u32 u2 = hlin2[(size_t)s2 * 64 + lane];
      u32 u3 = hlin2[(size_t)s3 * 64 + lane];
      float2 v0 = bf2_to_f2(u0), v1 = bf2_to_f2(u1);
      float2 v2 = bf2_to_f2(u2), v3 = bf2_to_f2(u3);
      acc.x = fmaf(w0, v0.x, acc.x); acc.y = fmaf(w0, v0.y, acc.y);
      acc.x = fmaf(w1, v1.x, acc.x); acc.y = fmaf(w1, v1.y, acc.y);
      acc.x = fmaf(w2, v2.x, acc.x); acc.y = fmaf(w2, v2.y, acc.y);
      acc.x = fmaf(w3, v3.x, acc.x); acc.y = fmaf(w3, v3.y, acc.y);
    }
    if (j + 2 <= m) {
      int s0 = __builtin_amdgcn_readlane(idxv, j + 0);
      int s1 = __builtin_amdgcn_readlane(idxv, j + 1);
      float w0 = __int_as_float(__builtin_amdgcn_readlane(wbits, j + 0));
      float w1 = __int_as_float(__builtin_amdgcn_readlane(wbits, j + 1));
      float2 v0 = bf2_to_f2(hlin2[(size_t)s0 * 64 + lane]);
      float2 v1 = bf2_to_f2(hlin2[(size_t)s1 * 64 + lane]);
      acc.x = fmaf(w0, v0.x, acc.x); acc.y = fmaf(w0, v0.y, acc.y);
      acc.x = fmaf(w1, v1.x, acc.x); acc.y = fmaf(w1, v1.y, acc.y);
      j += 2;
    }
    if (j < m) {
      int s0 = __builtin_amdgcn_readlane(idxv, j);
      float w0 = __int_as_float(__builtin_amdgcn_readlane(wbits, j));
      float2 v0 = bf2_to_f2(hlin2[(size_t)s0 * 64 + lane]);
      acc.x = fmaf(w0, v0.x, acc.x); acc.y = fmaf(w0, v0.y, acc.y);
    }
  }
  // relu fused here (layer output is post-activation)
  hout2[(size_t)node * 64 + lane] = f2_to_bf2(fmaxf(acc.x, 0.f), fmaxf(acc.y, 0.f));
}

// ---------------- fused pool + MLP head (h4 is bf16, already relu'd) ------
__global__ __launch_bounds__(256) void k_poolmlp(const uint2* __restrict__ h4u,
                                                 const int* __restrict__ gstart,
                                                 const float* __restrict__ xs,
                                                 const float* __restrict__ Wl1,
                                                 const float* __restrict__ bl1,
                                                 const float* __restrict__ Wl2,
                                                 const float* __restrict__ bl2,
                                                 float* __restrict__ out) {
  __shared__ float4 part[8][32];
  __shared__ float pooled[128];
  int g = blockIdx.x;
  int beg = gstart[g], end = gstart[g + 1];
  int tid = threadIdx.x;
  int cg = tid & 31;        // uint2 = 4 bf16 cols -> 32 groups x 4 = 128 cols
  int rg = tid >> 5;        // 8 rows per iteration
  float4 acc = make_float4(0.f, 0.f, 0.f, 0.f);
  for (int i = beg + rg; i < end; i += 8) {
    uint2 u = h4u[(size_t)i * 32 + cg];   // 8B/lane coalesced
    acc.x += __uint_as_float(u.x << 16);
    acc.y += __uint_as_float(u.x & 0xffff0000u);
    acc.z += __uint_as_float(u.y << 16);
    acc.w += __uint_as_float(u.y & 0xffff0000u);
  }
  part[rg][cg] = acc;
  __syncthreads();
  if (tid < 32) {
    float4 s = part[0][tid];
    #pragma unroll
    for (int r = 1; r < 8; ++r) {
      float4 v = part[r][tid];
      s.x += v.x; s.y += v.y; s.z += v.z; s.w += v.w;
    }
    float sc = 1.f / fmaxf((float)(end - beg), 1.f);
    pooled[tid * 4 + 0] = s.x * sc;
    pooled[tid * 4 + 1] = s.y * sc;
    pooled[tid * 4 + 2] = s.z * sc;
    pooled[tid * 4 + 3] = s.w * sc;
  }
  __syncthreads();
  if (tid < 64) {   // exactly wave 0
    float hj = bl1[tid];
    #pragma unroll 4
    for (int k = 0; k < 128; ++k) hj = fmaf(pooled[k], Wl1[k * 64 + tid], hj);
    const float* xr = xs + g * 4;
    #pragma unroll
    for (int k = 0; k < 4; ++k) hj = fmaf(xr[k], Wl1[(128 + k) * 64 + tid], hj);
    hj = fmaxf(hj, 0.f);
    float val = hj * Wl2[tid];
    #pragma unroll
    for (int off = 32; off > 0; off >>= 1) val += __shfl_down(val, off);
    if (tid == 0) out[g] = val + bl2[0];
  }
}

// ---------------- launcher ----------------

extern "C" void kernel_launch(void* const* d_in, const int* in_sizes, int n_in,
                              void* d_out, int out_size, void* d_ws, size_t ws_size,
                              hipStream_t stream) {
  const float* x    = (const float*)d_in[0];
  const int*   ei   = (const int*)d_in[1];
  const float* xs   = (const float*)d_in[2];
  const int*   batch= (const int*)d_in[3];
  const float* W0   = (const float*)d_in[4];
  const float* b0   = (const float*)d_in[5];
  const float* W1   = (const float*)d_in[6];
  const float* b1   = (const float*)d_in[7];
  const float* W2   = (const float*)d_in[8];
  const float* b2   = (const float*)d_in[9];
  const float* W3   = (const float*)d_in[10];
  const float* b3   = (const float*)d_in[11];
  const float* Wl1  = (const float*)d_in[12];
  const float* bl1  = (const float*)d_in[13];
  const float* Wl2  = (const float*)d_in[14];
  const float* bl2  = (const float*)d_in[15];
  const int* srcA = ei;        // edge_index[0]
  const int* dstA = ei + EE;   // edge_index[1]
  float* out = (float*)d_out;

  char* p = (char*)d_ws;
  auto take = [&](size_t bytes) { char* q = p; p += (bytes + 255) & ~(size_t)255; return q; };
  __bf16* hA   = (__bf16*)take((size_t)NN * 128 * 2);
  __bf16* hB   = (__bf16*)take((size_t)NN * 128 * 2);
  int*   cnt   = (int*)take((size_t)NN * 4);
  float* dinv  = (float*)take((size_t)NN * 4);
  int*   rowptr= (int*)take((size_t)(NN + 1) * 4);
  int*   fillc = (int*)take((size_t)NN * 4);
  int*   csr_s = (int*)take((size_t)EE * 4);
  float* csr_w = (float*)take((size_t)EE * 4);
  int*   bsum  = (int*)take(512 * 4);
  int*   gstart= (int*)take((size_t)(GG + 1) * 4);
  __bf16* Wt1  = (__bf16*)take(16384 * 2);
  __bf16* Wt2  = (__bf16*)take(16384 * 2);
  __bf16* Wt3  = (__bf16*)take(16384 * 2);

  // setup: degree, norm, CSR-by-dst, graph boundaries, W transposes
  k_init<<<NB, 256, 0, stream>>>(cnt, fillc, gstart);
  k_count<<<(EE + 255) / 256, 256, 0, stream>>>(dstA, cnt);
  k_dinv<<<NB, 256, 0, stream>>>(cnt, dinv);
  k_scan1<<<NB, 256, 0, stream>>>(cnt, rowptr, bsum);
  k_scan2<<<1, 512, 0, stream>>>(bsum);
  k_scan3<<<NB, 256, 0, stream>>>(rowptr, bsum);
  k_fill<<<(EE + 255) / 256, 256, 0, stream>>>(srcA, dstA, rowptr, fillc, dinv, csr_s, csr_w);
  k_gbound<<<NB, 256, 0, stream>>>(batch, gstart);
  k_wprep<<<64, 256, 0, stream>>>(W1, Wt1);
  k_wprep<<<64, 256, 0, stream>>>(W2, Wt2);
  k_wprep<<<64, 256, 0, stream>>>(W3, Wt3);

  // layer 0: x @ W0 -> hA (bf16); aggregate+bias+relu -> hB (bf16)
  k_mm0<<<(NN * 128 + 255) / 256, 256, 0, stream>>>(x, W0, hA);
  k_aggregate<<<(NN + 3) / 4, 256, 0, stream>>>((const u32*)hA, rowptr, csr_s, csr_w, dinv, b0, (u32*)hB);
  // layers 1-3: MFMA matmul (input already post-relu)
  k_mfma<<<(NN + 127) / 128, 256, 0, stream>>>(hB, Wt1, hA);
  k_aggregate<<<(NN + 3) / 4, 256, 0, stream>>>((const u32*)hA, rowptr, csr_s, csr_w, dinv, b1, (u32*)hB);
  k_mfma<<<(NN + 127) / 128, 256, 0, stream>>>(hB, Wt2, hA);
  k_aggregate<<<(NN + 3) / 4, 256, 0, stream>>>((const u32*)hA, rowptr, csr_s, csr_w, dinv, b2, (u32*)hB);
  k_mfma<<<(NN + 127) / 128, 256, 0, stream>>>(hB, Wt3, hA);
  k_aggregate<<<(NN + 3) / 4, 256, 0, stream>>>((const u32*)hA, rowptr, csr_s, csr_w, dinv, b3, (u32*)hB);

  // fused pool + head MLP (h already relu'd)
  k_poolmlp<<<GG, 256, 0, stream>>>((const uint2*)hB, gstart, xs, Wl1, bl1, Wl2, bl2, out);
}